// Round 6
// baseline (772.649 us; speedup 1.0000x reference)
//
#include <hip/hip_runtime.h>
#include <hip/hip_bf16.h>
#include <math.h>

#define SS 256
#define BB 8
#define TT 1024
#define DD 512
#define TSD 512
#define VV 32000
#define LN_EPS_F 1e-5f
#define VHALF 16000

typedef __attribute__((ext_vector_type(8))) short bf16x8;
typedef __attribute__((ext_vector_type(4))) float f32x4;

__device__ __forceinline__ unsigned short f2bf(float f) {
    union { float f; unsigned int u; } c; c.f = f;
    unsigned int u = c.u;
    return (unsigned short)((u + 0x7fffu + ((u >> 16) & 1u)) >> 16);
}
__device__ __forceinline__ float bf2f(unsigned short s) {
    union { unsigned int u; float f; } c; c.u = ((unsigned int)s) << 16;
    return c.f;
}

// async 16B global->LDS (wave-uniform LDS base + lane*16 by construction of callers)
__device__ __forceinline__ void glls16(const void* g, void* l) {
    __builtin_amdgcn_global_load_lds(
        (const __attribute__((address_space(1))) unsigned int*)g,
        (__attribute__((address_space(3))) unsigned int*)l,
        16, 0, 0);
}

// ---------------- reductions ----------------
__device__ __forceinline__ float warp_red_sum(float v) {
    for (int o = 32; o > 0; o >>= 1) v += __shfl_down(v, o, 64);
    return v;
}
__device__ __forceinline__ float warp_red_max(float v) {
    for (int o = 32; o > 0; o >>= 1) v = fmaxf(v, __shfl_down(v, o, 64));
    return v;
}
__device__ __forceinline__ float block_red_sum(float v, float* s) {
    int lane = threadIdx.x & 63, wid = threadIdx.x >> 6;
    v = warp_red_sum(v);
    __syncthreads();
    if (lane == 0) s[wid] = v;
    __syncthreads();
    float r = 0.f;
    int nw = blockDim.x >> 6;
    for (int i = 0; i < nw; i++) r += s[i];
    return r;
}
__device__ __forceinline__ float block_red_max(float v, float* s) {
    int lane = threadIdx.x & 63, wid = threadIdx.x >> 6;
    v = warp_red_max(v);
    __syncthreads();
    if (lane == 0) s[wid] = v;
    __syncthreads();
    float r = s[0];
    int nw = blockDim.x >> 6;
    for (int i = 1; i < nw; i++) r = fmaxf(r, s[i]);
    return r;
}

// ---------------- MFMA GEMM (NT): C[m,n] = act((sum_k A[m,k]*B[n,k] + bias[n]) * scale)
// 128x128 tile, BK=64, 256 threads = 4 waves (2x2), each wave 4x4 tiles of 16x16x32.
// LDS chunk layout: chunk c (16B = 8 bf16) holds (row = c>>3, kc_logical = (c&7) ^ (row&7)).
// ACT: 0 = none, 1 = tanh, 2 = exp + per-row sum accumulated into rsum[]
// SWZ: bijective XCD-aware blockIdx swizzle (m204)
// OUT_BF16 epilogue: stage tile in LDS (row-XOR swizzle), then contiguous 16B stores.
template<int IN_BF16, int OUT_BF16, int ACT, int SWZ>
__global__ __launch_bounds__(256) void mfma_gemm(
    const void* __restrict__ Ap, long long lda, long long aoff,
    const void* __restrict__ Bp, long long ldb, long long boff,
    const float* __restrict__ bias,
    void* __restrict__ Cp, long long ldc, long long coff,
    int K, float scale, float* __restrict__ rsum)
{
    __shared__ __align__(16) unsigned short smem[2 * 128 * 64];
    unsigned short* As = smem;
    unsigned short* Bs = smem + 128 * 64;
    const int tid = threadIdx.x;
    const int lane = tid & 63;
    const int wave = tid >> 6;
    const int wm = (wave >> 1) << 6;
    const int wn = (wave & 1) << 6;
    const int lane15 = lane & 15;
    const int quad = lane >> 4;

    int bx = blockIdx.x, by = blockIdx.y;
    if (SWZ) {
        unsigned int nx = gridDim.x;
        unsigned int nwg = nx * gridDim.y;
        unsigned int lin = blockIdx.y * nx + blockIdx.x;
        unsigned int q = nwg >> 3, r = nwg & 7u;
        unsigned int xcd = lin & 7u, loc = lin >> 3;
        unsigned int wg = (xcd < r ? xcd * (q + 1u) : r * (q + 1u) + (xcd - r) * q) + loc;
        bx = (int)(wg % nx);
        by = (int)(wg / nx);
    }
    const long long m0 = (long long)bx * 128;
    const long long n0 = (long long)by * 128;
    const long long z = blockIdx.z;

    f32x4 acc[4][4];
#pragma unroll
    for (int i = 0; i < 4; i++)
#pragma unroll
        for (int j = 0; j < 4; j++) acc[i][j] = (f32x4){0.f, 0.f, 0.f, 0.f};

    for (int k0 = 0; k0 < K; k0 += 64) {
        if (IN_BF16) {
            const unsigned short* A = (const unsigned short*)Ap + z * aoff;
            const unsigned short* B = (const unsigned short*)Bp + z * boff;
#pragma unroll
            for (int r = 0; r < 4; r++) {
                int c = r * 256 + tid;
                int row = c >> 3;
                int kc = (c & 7) ^ (row & 7);
                glls16(A + (m0 + row) * lda + k0 + kc * 8, &As[c * 8]);
                glls16(B + (n0 + row) * ldb + k0 + kc * 8, &Bs[c * 8]);
            }
        } else {
            const float* A = (const float*)Ap + z * aoff;
            const float* B = (const float*)Bp + z * boff;
#pragma unroll
            for (int r = 0; r < 4; r++) {
                int c = r * 256 + tid;
                int row = c >> 3;
                int kc = (c & 7) ^ (row & 7);
                const float* ga = A + (m0 + row) * lda + k0 + kc * 8;
                const float* gb = B + (n0 + row) * ldb + k0 + kc * 8;
                float4 a0 = *(const float4*)ga, a1 = *(const float4*)(ga + 4);
                float4 b0 = *(const float4*)gb, b1 = *(const float4*)(gb + 4);
                union { unsigned short us[8]; int4 v; } pa, pb;
                pa.us[0] = f2bf(a0.x); pa.us[1] = f2bf(a0.y); pa.us[2] = f2bf(a0.z); pa.us[3] = f2bf(a0.w);
                pa.us[4] = f2bf(a1.x); pa.us[5] = f2bf(a1.y); pa.us[6] = f2bf(a1.z); pa.us[7] = f2bf(a1.w);
                pb.us[0] = f2bf(b0.x); pb.us[1] = f2bf(b0.y); pb.us[2] = f2bf(b0.z); pb.us[3] = f2bf(b0.w);
                pb.us[4] = f2bf(b1.x); pb.us[5] = f2bf(b1.y); pb.us[6] = f2bf(b1.z); pb.us[7] = f2bf(b1.w);
                *(int4*)&As[c * 8] = pa.v;
                *(int4*)&Bs[c * 8] = pb.v;
            }
        }
        __syncthreads();
#pragma unroll
        for (int s = 0; s < 2; s++) {
            bf16x8 af[4], bfr[4];
#pragma unroll
            for (int i = 0; i < 4; i++) {
                int arow = wm + i * 16 + lane15;
                int kc = (s * 4 + quad) ^ (lane15 & 7);
                af[i] = *(const bf16x8*)&As[(arow * 8 + kc) * 8];
                int brow = wn + i * 16 + lane15;
                bfr[i] = *(const bf16x8*)&Bs[(brow * 8 + kc) * 8];
            }
#pragma unroll
            for (int i = 0; i < 4; i++)
#pragma unroll
                for (int j = 0; j < 4; j++)
                    acc[i][j] = __builtin_amdgcn_mfma_f32_16x16x32_bf16(af[i], bfr[j], acc[i][j], 0, 0, 0);
        }
        __syncthreads();
    }
    const long long zc = z * coff;
    float* sRowF = (float*)&smem[0];
    if (ACT == 2) {
        if (tid < 128) sRowF[tid] = 0.f;
        __syncthreads();
    }
#pragma unroll
    for (int i = 0; i < 4; i++) {
        float rs[4] = {0.f, 0.f, 0.f, 0.f};
#pragma unroll
        for (int j = 0; j < 4; j++) {
            float bv = bias ? bias[n0 + wn + j * 16 + lane15] : 0.f;
#pragma unroll
            for (int r2 = 0; r2 < 4; r2++) {
                float v = (acc[i][j][r2] + bv) * scale;
                if (ACT == 1) v = tanhf(v);
                if (ACT == 2) { v = __expf(v); rs[r2] += v; }
                acc[i][j][r2] = v;
            }
        }
        if (ACT == 2) {
#pragma unroll
            for (int r2 = 0; r2 < 4; r2++) {
                float s = rs[r2];
                s += __shfl_xor(s, 1, 64);
                s += __shfl_xor(s, 2, 64);
                s += __shfl_xor(s, 4, 64);
                s += __shfl_xor(s, 8, 64);
                if (lane15 == 0) atomicAdd(&sRowF[wm + i * 16 + quad * 4 + r2], s);
            }
        }
    }
    if (ACT == 2) {
        __syncthreads();
        if (tid < 128) atomicAdd(rsum + m0 + tid, sRowF[tid]);
        __syncthreads();
    }
    if (OUT_BF16) {
#pragma unroll
        for (int i = 0; i < 4; i++) {
#pragma unroll
            for (int r2 = 0; r2 < 4; r2++) {
                int lr = wm + i * 16 + quad * 4 + r2;
                int sw = (lr & 7) << 4;
#pragma unroll
                for (int j = 0; j < 4; j++) {
                    int lc = wn + j * 16 + lane15;
                    smem[lr * 128 + (lc ^ sw)] = f2bf(acc[i][j][r2]);
                }
            }
        }
        __syncthreads();
        unsigned short* Co = (unsigned short*)Cp + zc;
#pragma unroll
        for (int u = 0; u < 8; u++) {
            int e = tid + u * 256;
            int lr = e >> 4, lc8 = e & 15;
            int lcs = (lc8 * 8) ^ ((lr & 7) << 4);
            int4 vv4 = *(const int4*)&smem[lr * 128 + lcs];
            *(int4*)(Co + (m0 + lr) * ldc + n0 + lc8 * 8) = vv4;
        }
    } else {
#pragma unroll
        for (int i = 0; i < 4; i++) {
            long long rbase = m0 + wm + i * 16 + quad * 4;
#pragma unroll
            for (int j = 0; j < 4; j++) {
                long long col = n0 + wn + j * 16 + lane15;
#pragma unroll
                for (int r2 = 0; r2 < 4; r2++)
                    ((float*)Cp)[zc + (rbase + r2) * ldc + col] = acc[i][j][r2];
            }
        }
    }
}

// ---------------- big exp-GEMM: eb[m,v] = exp(tok[m,:].Wgen[v,:] + bgen[v]), rowsums -> gs
// 256x256 tile, BK=32, 512 threads = 8 waves (2M x 4N), per-wave 128x64 out (acc 8x4 f32x4).
// Counted-vmcnt double-buffer pipeline (T3/T4): raw s_barrier, vmcnt never drains to 0
// mid-loop; stage(kt+2) issued right after compute(kt), waits only for kt+1's loads.
// LDS 64 KB: A dbuf 2x16KB + B dbuf 2x16KB; chunk-XOR layout kc=(c&3)^(row&3) (2-way free).
__global__ __launch_bounds__(512) void mfma_gemm_big(
    const unsigned short* __restrict__ A,   // tokb  [2048][512]
    const unsigned short* __restrict__ B,   // wgenb [32000][512]
    const float* __restrict__ bias,         // bgen
    unsigned short* __restrict__ C,         // eb [2048][32000]
    float* __restrict__ rsum)               // gs
{
    __shared__ __align__(16) unsigned short smem[32768];   // 64 KB
    const int tid = threadIdx.x;
    const int lane = tid & 63;
    const int wave = tid >> 6;           // 0..7
    const int lane15 = lane & 15;
    const int quad = lane >> 4;
    const int wm = (wave >> 2) << 7;     // 0 / 128
    const int wn = (wave & 3) << 6;      // 0 / 64 / 128 / 192

    // bijective XCD swizzle: nwg = 8*125 = 1000, 1000 % 8 == 0
    unsigned int lin = blockIdx.y * 8u + blockIdx.x;
    unsigned int wg = (lin & 7u) * 125u + (lin >> 3);
    const long long m0 = (long long)(wg & 7u) * 256;     // wg % gridDim.x(=8)
    const long long n0 = (long long)(wg >> 3) * 256;     // wg / 8

    f32x4 acc[8][4];
#pragma unroll
    for (int i = 0; i < 8; i++)
#pragma unroll
        for (int j = 0; j < 4; j++) acc[i][j] = (f32x4){0.f, 0.f, 0.f, 0.f};

#define STAGE_BIG(kt, buf)                                                        \
    {                                                                             \
        const int k0s = (kt) << 5;                                                \
        unsigned short* Asb = &smem[(buf) * 8192];                                \
        unsigned short* Bsb = &smem[16384 + (buf) * 8192];                        \
        _Pragma("unroll")                                                         \
        for (int r = 0; r < 2; r++) {                                             \
            int c = r * 512 + tid;                                                \
            int row = c >> 2;                                                     \
            int kc = (c & 3) ^ (row & 3);                                         \
            glls16(A + (m0 + row) * 512 + k0s + kc * 8, &Asb[c * 8]);             \
            glls16(B + (n0 + row) * 512 + k0s + kc * 8, &Bsb[c * 8]);             \
        }                                                                         \
    }

    STAGE_BIG(0, 0)
    STAGE_BIG(1, 1)
    asm volatile("s_waitcnt vmcnt(4)" ::: "memory");
    __builtin_amdgcn_s_barrier();

    for (int kt = 0; kt < 16; kt++) {
        const int buf = kt & 1;
        const unsigned short* Asb = &smem[buf * 8192];
        const unsigned short* Bsb = &smem[16384 + buf * 8192];
        const int kcp = quad ^ (lane15 & 3);
        bf16x8 bfr[4];
#pragma unroll
        for (int j = 0; j < 4; j++) {
            int brow = wn + j * 16 + lane15;
            bfr[j] = *(const bf16x8*)&Bsb[(brow * 4 + kcp) * 8];
        }
#pragma unroll
        for (int ih = 0; ih < 2; ih++) {
            bf16x8 af[4];
#pragma unroll
            for (int i2 = 0; i2 < 4; i2++) {
                int arow = wm + (ih * 4 + i2) * 16 + lane15;
                af[i2] = *(const bf16x8*)&Asb[(arow * 4 + kcp) * 8];
            }
            __builtin_amdgcn_s_setprio(1);
#pragma unroll
            for (int i2 = 0; i2 < 4; i2++)
#pragma unroll
                for (int j = 0; j < 4; j++)
                    acc[ih * 4 + i2][j] = __builtin_amdgcn_mfma_f32_16x16x32_bf16(
                        af[i2], bfr[j], acc[ih * 4 + i2][j], 0, 0, 0);
            __builtin_amdgcn_s_setprio(0);
        }
        __builtin_amdgcn_s_barrier();          // all waves done reading buf
        if (kt < 14) {
            STAGE_BIG(kt + 2, buf)
            asm volatile("s_waitcnt vmcnt(4)" ::: "memory");   // kt+1's loads landed
        } else {
            asm volatile("s_waitcnt vmcnt(0)" ::: "memory");
        }
        __builtin_amdgcn_s_barrier();          // next buf ready for all
    }
#undef STAGE_BIG

    // ---- epilogue: exp + rowsums + LDS-staged coalesced bf16 store (two 128-row halves)
    float* sRowF = (float*)smem;
    if (tid < 256) sRowF[tid] = 0.f;
    __syncthreads();
#pragma unroll
    for (int i = 0; i < 8; i++) {
        float rs[4] = {0.f, 0.f, 0.f, 0.f};
#pragma unroll
        for (int j = 0; j < 4; j++) {
            float bv = bias[n0 + wn + j * 16 + lane15];
#pragma unroll
            for (int r2 = 0; r2 < 4; r2++) {
                float v = __expf(acc[i][j][r2] + bv);
                acc[i][j][r2] = v;
                rs[r2] += v;
            }
        }
#pragma unroll
        for (int r2 = 0; r2 < 4; r2++) {
            float s = rs[r2];
            s += __shfl_xor(s, 1, 64);
            s += __shfl_xor(s, 2, 64);
            s += __shfl_xor(s, 4, 64);
            s += __shfl_xor(s, 8, 64);
            if (lane15 == 0) atomicAdd(&sRowF[wm + i * 16 + quad * 4 + r2], s);
        }
    }
    __syncthreads();
    if (tid < 256) atomicAdd(rsum + m0 + tid, sRowF[tid]);
    __syncthreads();
#pragma unroll
    for (int h = 0; h < 2; h++) {
        if ((wave >> 2) == h) {
#pragma unroll
            for (int i = 0; i < 8; i++)
#pragma unroll
                for (int r2 = 0; r2 < 4; r2++) {
                    int lrl = i * 16 + quad * 4 + r2;      // 0..127 local row
                    int sw = (lrl & 7) << 4;
#pragma unroll
                    for (int j = 0; j < 4; j++) {
                        int lc = wn + j * 16 + lane15;
                        smem[lrl * 256 + (lc ^ sw)] = f2bf(acc[i][j][r2]);
                    }
                }
        }
        __syncthreads();
#pragma unroll
        for (int u = 0; u < 8; u++) {
            int e = tid + u * 512;
            int lrl = e >> 5, ch = e & 31;
            int lcs = (ch * 8) ^ ((lrl & 7) << 4);
            int4 vv4 = *(const int4*)&smem[lrl * 256 + lcs];
            *(int4*)(C + (m0 + h * 128 + lrl) * 32000LL + n0 + ch * 8) = vv4;
        }
        __syncthreads();
    }
}

// ---------------- attention softmax over T, masked, in place; also emits bf16 copy
__global__ __launch_bounds__(256) void attn_softmax(
    float* __restrict__ scores, unsigned short* __restrict__ scores_bf,
    const unsigned char* __restrict__ mask)
{
    __shared__ float red[4];
    int row = blockIdx.x;
    int b = row & (BB - 1);
    float* p = scores + (long long)row * TT;
    unsigned short* pb = scores_bf + (long long)row * TT;
    const unsigned char* mr = mask + (long long)b * TT;
    float vals[TT / 256];
    float lmax = -3.0e38f;
#pragma unroll
    for (int i = 0; i < TT / 256; i++) {
        int t = threadIdx.x + i * 256;
        float s = p[t];
        if (mr[t]) s = -1.0e9f;
        vals[i] = s;
        lmax = fmaxf(lmax, s);
    }
    float gmax = block_red_max(lmax, red);
    float lsum = 0.f;
#pragma unroll
    for (int i = 0; i < TT / 256; i++) {
        vals[i] = __expf(vals[i] - gmax);
        lsum += vals[i];
    }
    float gsum = block_red_sum(lsum, red);
    float inv = 1.f / gsum;
#pragma unroll
    for (int i = 0; i < TT / 256; i++) {
        float v = vals[i] * inv;
        int t = threadIdx.x + i * 256;
        p[t] = v;
        pb[t] = f2bf(v);
    }
}

// ---------------- transpose+cast: v[8192=(t,b)][512] f32 -> vT[b][d][t] bf16
__global__ __launch_bounds__(256) void transpose_v(
    const float* __restrict__ v, unsigned short* __restrict__ vT)
{
    __shared__ float tile[64][65];
    int b = blockIdx.z;
    int t0 = blockIdx.x * 64, d0 = blockIdx.y * 64;
    int tx = threadIdx.x & 63, ty = threadIdx.x >> 6;
#pragma unroll
    for (int i = ty; i < 64; i += 4)
        tile[i][tx] = v[((long long)(t0 + i) * BB + b) * DD + d0 + tx];
    __syncthreads();
#pragma unroll
    for (int i = ty; i < 64; i += 4)
        vT[((long long)b * DD + d0 + i) * TT + t0 + tx] = f2bf(tile[tx][i]);
}

// ---------------- y = LayerNorm(outs + xo) * g + b
__global__ __launch_bounds__(256) void add_ln(
    const float* __restrict__ outs, const float* __restrict__ xo,
    const float* __restrict__ g, const float* __restrict__ bln,
    float* __restrict__ y)
{
    __shared__ float red[4];
    int row = blockIdx.x;
    const float* o = outs + (long long)row * DD;
    const float* xp = xo + (long long)row * DD;
    float x[DD / 256];
    float s = 0.f;
#pragma unroll
    for (int i = 0; i < DD / 256; i++) {
        int d = threadIdx.x + i * 256;
        x[i] = o[d] + xp[d];
        s += x[i];
    }
    float mu = block_red_sum(s, red) * (1.f / DD);
    float s2 = 0.f;
#pragma unroll
    for (int i = 0; i < DD / 256; i++) {
        float dv = x[i] - mu;
        s2 += dv * dv;
    }
    float var = block_red_sum(s2, red) * (1.f / DD);
    float rinv = rsqrtf(var + LN_EPS_F);
#pragma unroll
    for (int i = 0; i < DD / 256; i++) {
        int d = threadIdx.x + i * 256;
        y[(long long)row * DD + d] = (x[i] - mu) * rinv * g[d] + bln[d];
    }
}

// ---------------- 2-way gate softmax per row (tok in bf16)
__global__ __launch_bounds__(256) void div_gates(
    const unsigned short* __restrict__ tok, const float* __restrict__ Wdiv,
    const float* __restrict__ bdiv, float* __restrict__ gen, float* __restrict__ cop)
{
    __shared__ float red[4];
    int row = blockIdx.x;
    const unsigned short* t = tok + (long long)row * TSD;
    float a0 = 0.f, a1 = 0.f;
#pragma unroll
    for (int i = 0; i < TSD / 256; i++) {
        int d = threadIdx.x + i * 256;
        float tv = bf2f(t[d]);
        a0 = fmaf(tv, Wdiv[d], a0);
        a1 = fmaf(tv, Wdiv[TSD + d], a1);
    }
    a0 = block_red_sum(a0, red);
    a1 = block_red_sum(a1, red);
    if (threadIdx.x == 0) {
        a0 += bdiv[0];
        a1 += bdiv[1];
        float m = fmaxf(a0, a1);
        float e0 = __expf(a0 - m), e1 = __expf(a1 - m);
        float inv = 1.f / (e0 + e1);
        gen[row] = e0 * inv;
        cop[row] = e1 * inv;
    }
}

// ---------------- fused copy-scatter + normalize + log
__global__ __launch_bounds__(512) void copy_log_final(
    const unsigned short* __restrict__ eb, const float* __restrict__ attn,
    const float* __restrict__ cop, const float* __restrict__ gen,
    const float* __restrict__ gs, const int* __restrict__ seq,
    float* __restrict__ out)
{
    __shared__ __align__(16) float pc[VHALF];          // 64000 B
    const int tid = threadIdx.x;
    const int row = blockIdx.x;          // (s,b) row, b = row & 7
    const int half = blockIdx.y;
    const int base = half * VHALF;
    const int b = row & (BB - 1);

    for (int i = tid; i < VHALF; i += 512) pc[i] = 0.f;
    __syncthreads();

    const float cv = cop[row];
    const float* arow = attn + (long long)row * TT;
#pragma unroll
    for (int it = 0; it < 2; it++) {
        int t = tid + it * 512;
        int idx = seq[t * BB + b];
        int loc = idx - base;
        if (loc >= 0 && loc < VHALF)
            atomicAdd(&pc[loc], cv * arow[t]);
    }
    __syncthreads();

    const float ginv = gen[row] / gs[row];
    const unsigned short* erow = eb + (long long)row * VV + base;
    float* orow = out + (long long)row * VV + base;
    const float4* pc4 = (const float4*)pc;
    for (int c = tid; c < VHALF / 8; c += 512) {
        bf16x8 ev = *(const bf16x8*)(erow + c * 8);
        float4 p0 = pc4[c * 2], p1 = pc4[c * 2 + 1];
        float4 o0, o1;
        o0.x = __logf(fmaf(bf2f((unsigned short)ev[0]), ginv, p0.x) + 1e-12f);
        o0.y = __logf(fmaf(bf2f((unsigned short)ev[1]), ginv, p0.y) + 1e-12f);
        o0.z = __logf(fmaf(bf2f((unsigned short)ev[2]), ginv, p0.z) + 1e-12f);
        o0.w = __logf(fmaf(bf2f((unsigned short)ev[3]), ginv, p0.w) + 1e-12f);
        o1.x = __logf(fmaf(bf2f((unsigned short)ev[4]), ginv, p1.x) + 1e-12f);
        o1.y = __logf(fmaf(bf2f((unsigned short)ev[5]), ginv, p1.y) + 1e-12f);
        o1.z = __logf(fmaf(bf2f((unsigned short)ev[6]), ginv, p1.z) + 1e-12f);
        o1.w = __logf(fmaf(bf2f((unsigned short)ev[7]), ginv, p1.w) + 1e-12f);
        ((float4*)orow)[c * 2] = o0;
        ((float4*)orow)[c * 2 + 1] = o1;
    }
}

// ---------------- f32 -> bf16 cast (8 elems/thread), also zeroes gs accumulator
__global__ __launch_bounds__(256) void cast_f32_bf16(
    const float* __restrict__ in, unsigned short* __restrict__ o, long long n8,
    float* __restrict__ gszero)
{
    long long i = (long long)blockIdx.x * 256 + threadIdx.x;
    if (gszero && blockIdx.x < 8) gszero[blockIdx.x * 256 + threadIdx.x] = 0.f;
    if (i >= n8) return;
    const float4* p = (const float4*)in + i * 2;
    float4 a = p[0], b = p[1];
    union { unsigned short us[8]; int4 v; } pk;
    pk.us[0] = f2bf(a.x); pk.us[1] = f2bf(a.y); pk.us[2] = f2bf(a.z); pk.us[3] = f2bf(a.w);
    pk.us[4] = f2bf(b.x); pk.us[5] = f2bf(b.y); pk.us[6] = f2bf(b.z); pk.us[7] = f2bf(b.w);
    ((int4*)o)[i] = pk.v;
}

extern "C" void kernel_launch(void* const* d_in, const int* in_sizes, int n_in,
                              void* d_out, int out_size, void* d_ws, size_t ws_size,
                              hipStream_t stream)
{
    const float* outs = (const float*)d_in[0];
    const float* gstate = (const float*)d_in[1];
    const unsigned char* mask = (const unsigned char*)d_in[2];
    const int* seq = (const int*)d_in[3];
    const float* Wq = (const float*)d_in[4];  const float* bq = (const float*)d_in[5];
    const float* Wk = (const float*)d_in[6];  const float* bk = (const float*)d_in[7];
    const float* Wv = (const float*)d_in[8];  const float* bv = (const float*)d_in[9];
    const float* Wo = (const float*)d_in[10]; const float* bo = (const float*)d_in[11];
    const float* lng = (const float*)d_in[12]; const float* lnb = (const float*)d_in[13];
    const float* Wt = (const float*)d_in[14]; const float* bt = (const float*)d_in[15];
    const float* Wgen = (const float*)d_in[16]; const float* bgen = (const float*)d_in[17];
    const float* Wdiv = (const float*)d_in[18]; const float* bdiv = (const float*)d_in[19];
    float* out = (float*)d_out;

    char* w = (char*)d_ws;
    unsigned short* qb    = (unsigned short*)w; w += 2048LL * 512 * 2;   // q bf16
    unsigned short* kb    = (unsigned short*)w; w += 8192LL * 512 * 2;   // k bf16
    unsigned short* tokb  = (unsigned short*)w; w += 2048LL * 512 * 2;   // tok bf16
    unsigned short* wgenb = (unsigned short*)w; w += 32000LL * 512 * 2;  // Wgen bf16
    unsigned short* vTb   = (unsigned short*)w; w += 8LL * 512 * 1024 * 2; // v^T bf16 [b][d][t]
    unsigned short* attnb = (unsigned short*)w; w += 2048LL * 1024 * 2;  // attn bf16
    unsigned short* eb    = (unsigned short*)w; w += 2048LL * 32000 * 2; // E = exp(logits) bf16
    float* vv   = (float*)w; w += 8192LL * 512 * 4;
    float* attn = (float*)w; w += 2048LL * 1024 * 4;
    float* ctx  = (float*)w; w += 2048LL * 512 * 4;
    float* xo   = (float*)w; w += 2048LL * 512 * 4;
    float* y    = (float*)w; w += 2048LL * 512 * 4;
    float* gen  = (float*)w; w += 2048 * 4;
    float* cop  = (float*)w; w += 2048 * 4;
    float* gs   = (float*)w; w += 2048 * 4;

    float qscale = 1.0f / sqrtf((float)DD);
    dim3 blk(256);

    cast_f32_bf16<<<8000, blk, 0, stream>>>(Wgen, wgenb, 32000LL * 512 / 8, gs);

    // q = (outs @ Wq.T + bq)*scale -> bf16   [2048 x 512]
    mfma_gemm<0, 1, 0, 0><<<dim3(16, 4, 1), blk, 0, stream>>>(outs, 512, 0, Wq, 512, 0, bq, qb, 512, 0, 512, qscale, nullptr);
    // k = gstate @ Wk.T + bk -> bf16         [8192 x 512]
    mfma_gemm<0, 1, 0, 0><<<dim3(64, 4, 1), blk, 0, stream>>>(gstate, 512, 0, Wk, 512, 0, bk, kb, 512, 0, 512, 1.f, nullptr);
    // v = gstate @ Wv.T + bv -> f32          [8192 x 512]
    mfma_gemm<0, 0, 0, 0><<<dim3(64, 4, 1), blk, 0, stream>>>(gstate, 512, 0, Wv, 512, 0, bv, vv, 512, 0, 512, 1.f, nullptr);
    // vT[b][d][t] bf16
    transpose_v<<<dim3(16, 8, 8), blk, 0, stream>>>(vv, vTb);
    // scores[s,b,t] = q . k per batch        [256 x 1024, z=8]
    mfma_gemm<1, 0, 0, 0><<<dim3(2, 8, 8), blk, 0, stream>>>(qb, 4096, 512, kb, 4096, 512, nullptr, attn, 8192, 1024, 512, 1.f, nullptr);
    attn_softmax<<<2048, blk, 0, stream>>>(attn, attnb, mask);
    // ctx = attn @ v per batch via MFMA: C[s,d] = sum_t attnb[s,t] * vT[d,t]
    mfma_gemm<1, 0, 0, 0><<<dim3(2, 4, 8), blk, 0, stream>>>(attnb, 8192, 1024, vTb, 1024, 524288, nullptr, ctx, 4096, 512, 1024, 1.f, nullptr);
    // xo = ctx @ Wo.T + bo
    mfma_gemm<0, 0, 0, 0><<<dim3(16, 4, 1), blk, 0, stream>>>(ctx, 512, 0, Wo, 512, 0, bo, xo, 512, 0, 512, 1.f, nullptr);
    add_ln<<<2048, blk, 0, stream>>>(outs, xo, lng, lnb, y);
    // tok = tanh(y @ Wt.T + bt) -> bf16
    mfma_gemm<0, 1, 1, 0><<<dim3(16, 4, 1), blk, 0, stream>>>(y, 512, 0, Wt, 512, 0, bt, tokb, 512, 0, 512, 1.f, nullptr);
    div_gates<<<2048, blk, 0, stream>>>(tokb, Wdiv, bdiv, gen, cop);
    // E = exp(tok @ Wgen.T + bgen) -> eb (bf16), row sums -> gs   [2048 x 32000]
    mfma_gemm_big<<<dim3(8, 125), dim3(512), 0, stream>>>(tokb, wgenb, bgen, eb, gs);
    // ll = log(E*gen/gs + copy + 1e-12), copy scattered via LDS
    copy_log_final<<<dim3(2048, 2), dim3(512), 0, stream>>>(eb, attn, cop, gen, gs, seq, out);
}

// Round 7
// 702.298 us; speedup vs baseline: 1.1002x; 1.1002x over previous
//
#include <hip/hip_runtime.h>
#include <hip/hip_bf16.h>
#include <math.h>

#define SS 256
#define BB 8
#define TT 1024
#define DD 512
#define TSD 512
#define VV 32000
#define LN_EPS_F 1e-5f
#define VHALF 16000

typedef __attribute__((ext_vector_type(8))) short bf16x8;
typedef __attribute__((ext_vector_type(4))) float f32x4;

__device__ __forceinline__ unsigned short f2bf(float f) {
    union { float f; unsigned int u; } c; c.f = f;
    unsigned int u = c.u;
    return (unsigned short)((u + 0x7fffu + ((u >> 16) & 1u)) >> 16);
}
__device__ __forceinline__ float bf2f(unsigned short s) {
    union { unsigned int u; float f; } c; c.u = ((unsigned int)s) << 16;
    return c.f;
}

// async 16B global->LDS (wave-uniform LDS base + lane*16 by construction of callers)
__device__ __forceinline__ void glls16(const void* g, void* l) {
    __builtin_amdgcn_global_load_lds(
        (const __attribute__((address_space(1))) unsigned int*)g,
        (__attribute__((address_space(3))) unsigned int*)l,
        16, 0, 0);
}

// ---------------- reductions ----------------
__device__ __forceinline__ float warp_red_sum(float v) {
    for (int o = 32; o > 0; o >>= 1) v += __shfl_down(v, o, 64);
    return v;
}
__device__ __forceinline__ float warp_red_max(float v) {
    for (int o = 32; o > 0; o >>= 1) v = fmaxf(v, __shfl_down(v, o, 64));
    return v;
}
__device__ __forceinline__ float block_red_sum(float v, float* s) {
    int lane = threadIdx.x & 63, wid = threadIdx.x >> 6;
    v = warp_red_sum(v);
    __syncthreads();
    if (lane == 0) s[wid] = v;
    __syncthreads();
    float r = 0.f;
    int nw = blockDim.x >> 6;
    for (int i = 0; i < nw; i++) r += s[i];
    return r;
}
__device__ __forceinline__ float block_red_max(float v, float* s) {
    int lane = threadIdx.x & 63, wid = threadIdx.x >> 6;
    v = warp_red_max(v);
    __syncthreads();
    if (lane == 0) s[wid] = v;
    __syncthreads();
    float r = s[0];
    int nw = blockDim.x >> 6;
    for (int i = 1; i < nw; i++) r = fmaxf(r, s[i]);
    return r;
}

// ---------------- MFMA GEMM body (NT): C[m,n] = act((sum_k A[m,k]*B[n,k] + bias[n]) * scale)
// 128x128 tile, BK=64, 256 threads = 4 waves (2x2), each wave 4x4 tiles of 16x16x32.
// LDS chunk layout: chunk c (16B = 8 bf16) holds (row = c>>3, kc_logical = (c&7) ^ (row&7)).
// ACT: 0 = none, 1 = tanh, 2 = exp + per-row sum accumulated into rsum[]
// OUT_MODE: 0 = f32 scattered, 1 = bf16 LDS-staged coalesced, 2 = bf16 direct into vT[b][d][t]
template<int IN_BF16, int OUT_MODE, int ACT>
__device__ __forceinline__ void gemm_body(
    unsigned short* smem, int bx, int by, int z,
    const void* __restrict__ Ap, long long lda, long long aoff,
    const void* __restrict__ Bp, long long ldb, long long boff,
    const float* __restrict__ bias,
    void* __restrict__ Cp, long long ldc, long long coff,
    int K, float scale, float* __restrict__ rsum)
{
    unsigned short* As = smem;
    unsigned short* Bs = smem + 128 * 64;
    const int tid = threadIdx.x;
    const int lane = tid & 63;
    const int wave = tid >> 6;
    const int wm = (wave >> 1) << 6;
    const int wn = (wave & 1) << 6;
    const int lane15 = lane & 15;
    const int quad = lane >> 4;
    const long long m0 = (long long)bx * 128;
    const long long n0 = (long long)by * 128;

    f32x4 acc[4][4];
#pragma unroll
    for (int i = 0; i < 4; i++)
#pragma unroll
        for (int j = 0; j < 4; j++) acc[i][j] = (f32x4){0.f, 0.f, 0.f, 0.f};

    for (int k0 = 0; k0 < K; k0 += 64) {
        if (IN_BF16) {
            const unsigned short* A = (const unsigned short*)Ap + z * aoff;
            const unsigned short* B = (const unsigned short*)Bp + z * boff;
#pragma unroll
            for (int r = 0; r < 4; r++) {
                int c = r * 256 + tid;
                int row = c >> 3;
                int kc = (c & 7) ^ (row & 7);
                glls16(A + (m0 + row) * lda + k0 + kc * 8, &As[c * 8]);
                glls16(B + (n0 + row) * ldb + k0 + kc * 8, &Bs[c * 8]);
            }
        } else {
            const float* A = (const float*)Ap + z * aoff;
            const float* B = (const float*)Bp + z * boff;
#pragma unroll
            for (int r = 0; r < 4; r++) {
                int c = r * 256 + tid;
                int row = c >> 3;
                int kc = (c & 7) ^ (row & 7);
                const float* ga = A + (m0 + row) * lda + k0 + kc * 8;
                const float* gb = B + (n0 + row) * ldb + k0 + kc * 8;
                float4 a0 = *(const float4*)ga, a1 = *(const float4*)(ga + 4);
                float4 b0 = *(const float4*)gb, b1 = *(const float4*)(gb + 4);
                union { unsigned short us[8]; int4 v; } pa, pb;
                pa.us[0] = f2bf(a0.x); pa.us[1] = f2bf(a0.y); pa.us[2] = f2bf(a0.z); pa.us[3] = f2bf(a0.w);
                pa.us[4] = f2bf(a1.x); pa.us[5] = f2bf(a1.y); pa.us[6] = f2bf(a1.z); pa.us[7] = f2bf(a1.w);
                pb.us[0] = f2bf(b0.x); pb.us[1] = f2bf(b0.y); pb.us[2] = f2bf(b0.z); pb.us[3] = f2bf(b0.w);
                pb.us[4] = f2bf(b1.x); pb.us[5] = f2bf(b1.y); pb.us[6] = f2bf(b1.z); pb.us[7] = f2bf(b1.w);
                *(int4*)&As[c * 8] = pa.v;
                *(int4*)&Bs[c * 8] = pb.v;
            }
        }
        __syncthreads();
#pragma unroll
        for (int s = 0; s < 2; s++) {
            bf16x8 af[4], bfr[4];
#pragma unroll
            for (int i = 0; i < 4; i++) {
                int arow = wm + i * 16 + lane15;
                int kc = (s * 4 + quad) ^ (lane15 & 7);
                af[i] = *(const bf16x8*)&As[(arow * 8 + kc) * 8];
                int brow = wn + i * 16 + lane15;
                bfr[i] = *(const bf16x8*)&Bs[(brow * 8 + kc) * 8];
            }
#pragma unroll
            for (int i = 0; i < 4; i++)
#pragma unroll
                for (int j = 0; j < 4; j++)
                    acc[i][j] = __builtin_amdgcn_mfma_f32_16x16x32_bf16(af[i], bfr[j], acc[i][j], 0, 0, 0);
        }
        __syncthreads();
    }
    // ---- epilogue: C/D layout col=lane&15, row=quad*4+reg [m89/m91 verified] ----
    const long long zc = z * coff;
    float* sRowF = (float*)&smem[0];
    if (ACT == 2) {
        if (tid < 128) sRowF[tid] = 0.f;
        __syncthreads();
    }
#pragma unroll
    for (int i = 0; i < 4; i++) {
        float rs[4] = {0.f, 0.f, 0.f, 0.f};
#pragma unroll
        for (int j = 0; j < 4; j++) {
            float bv = bias ? bias[n0 + wn + j * 16 + lane15] : 0.f;
#pragma unroll
            for (int r2 = 0; r2 < 4; r2++) {
                float v = (acc[i][j][r2] + bv) * scale;
                if (ACT == 1) v = tanhf(v);
                if (ACT == 2) { v = __expf(v); rs[r2] += v; }
                acc[i][j][r2] = v;
            }
        }
        if (ACT == 2) {
#pragma unroll
            for (int r2 = 0; r2 < 4; r2++) {
                float s = rs[r2];
                s += __shfl_xor(s, 1, 64);
                s += __shfl_xor(s, 2, 64);
                s += __shfl_xor(s, 4, 64);
                s += __shfl_xor(s, 8, 64);
                if (lane15 == 0) atomicAdd(&sRowF[wm + i * 16 + quad * 4 + r2], s);
            }
        }
    }
    if (ACT == 2) {
        __syncthreads();
        if (tid < 128) atomicAdd(rsum + m0 + tid, sRowF[tid]);
        __syncthreads();
    }
    if (OUT_MODE >= 1) {
        // stage the 128x128 bf16 tile in smem (32 KB), row-XOR swizzle to spread banks
#pragma unroll
        for (int i = 0; i < 4; i++) {
#pragma unroll
            for (int r2 = 0; r2 < 4; r2++) {
                int lr = wm + i * 16 + quad * 4 + r2;
                int sw = (lr & 7) << 4;
#pragma unroll
                for (int j = 0; j < 4; j++) {
                    int lc = wn + j * 16 + lane15;
                    smem[lr * 128 + (lc ^ sw)] = f2bf(acc[i][j][r2]);
                }
            }
        }
        __syncthreads();
        if (OUT_MODE == 1) {
            unsigned short* Co = (unsigned short*)Cp + zc;
#pragma unroll
            for (int u = 0; u < 8; u++) {
                int e = tid + u * 256;
                int lr = e >> 4, lc8 = e & 15;
                int lcs = (lc8 * 8) ^ ((lr & 7) << 4);
                int4 vv4 = *(const int4*)&smem[lr * 128 + lcs];
                *(int4*)(Co + (m0 + lr) * ldc + n0 + lc8 * 8) = vv4;
            }
        } else {
            // OUT_MODE 2: tile rows m = t*8+b; write vT[b][d][t] (32B per (b,d) pair)
            unsigned short* vT = (unsigned short*)Cp;
            const int t0g = (int)(m0 >> 3);
#pragma unroll
            for (int u = 0; u < 4; u++) {
                int e = tid + u * 256;
                int b = e >> 7, dl = e & 127;
                int sw = (b & 7) << 4;
                union { unsigned short us[16]; int4 v[2]; } pk;
#pragma unroll
                for (int tl = 0; tl < 16; tl++)
                    pk.us[tl] = smem[(tl * 8 + b) * 128 + (dl ^ sw)];
                unsigned short* dst = vT + (long long)b * (DD * TT) + (long long)(n0 + dl) * TT + t0g;
                *(int4*)dst = pk.v[0];
                *(int4*)(dst + 8) = pk.v[1];
            }
        }
        __syncthreads();
    } else {
#pragma unroll
        for (int i = 0; i < 4; i++) {
            long long rbase = m0 + wm + i * 16 + quad * 4;
#pragma unroll
            for (int j = 0; j < 4; j++) {
                long long col = n0 + wn + j * 16 + lane15;
#pragma unroll
                for (int r2 = 0; r2 < 4; r2++)
                    ((float*)Cp)[zc + (rbase + r2) * ldc + col] = acc[i][j][r2];
            }
        }
    }
}

// ---------------- standalone GEMM kernel wrapper
template<int IN_BF16, int OUT_MODE, int ACT, int SWZ>
__global__ __launch_bounds__(256) void mfma_gemm(
    const void* __restrict__ Ap, long long lda, long long aoff,
    const void* __restrict__ Bp, long long ldb, long long boff,
    const float* __restrict__ bias,
    void* __restrict__ Cp, long long ldc, long long coff,
    int K, float scale, float* __restrict__ rsum)
{
    __shared__ __align__(16) unsigned short smem[2 * 128 * 64];
    int bx = blockIdx.x, by = blockIdx.y;
    if (SWZ) {
        unsigned int nx = gridDim.x;
        unsigned int nwg = nx * gridDim.y;
        unsigned int lin = blockIdx.y * nx + blockIdx.x;
        unsigned int q = nwg >> 3, r = nwg & 7u;
        unsigned int xcd = lin & 7u, loc = lin >> 3;
        unsigned int wg = (xcd < r ? xcd * (q + 1u) : r * (q + 1u) + (xcd - r) * q) + loc;
        bx = (int)(wg % nx);
        by = (int)(wg / nx);
    }
    gemm_body<IN_BF16, OUT_MODE, ACT>(smem, bx, by, blockIdx.z,
        Ap, lda, aoff, Bp, ldb, boff, bias, Cp, ldc, coff, K, scale, rsum);
}

// ---------------- fused front: q-GEMM | k-GEMM | v-GEMM(->vT) | Wgen cast + gs zero
// One launch; jobs selected by flattened blockIdx so independent ops run concurrently.
__global__ __launch_bounds__(256) void front_fused(
    const float* __restrict__ outs, const float* __restrict__ Wq, const float* __restrict__ bq,
    const float* __restrict__ gstate, const float* __restrict__ Wk, const float* __restrict__ bk,
    const float* __restrict__ Wv, const float* __restrict__ bv,
    unsigned short* __restrict__ qb, unsigned short* __restrict__ kb,
    unsigned short* __restrict__ vTb,
    const float* __restrict__ Wgen, unsigned short* __restrict__ wgenb,
    float* __restrict__ gs, float qscale)
{
    extern __shared__ __align__(16) unsigned short dsm[];
    const int bid = blockIdx.x;
    if (bid < 64) {
        // q = (outs @ Wq.T + bq)*qscale -> bf16  [2048 x 512], grid 16x4
        gemm_body<0, 1, 0>(dsm, bid & 15, bid >> 4, 0,
            outs, 512, 0, Wq, 512, 0, bq, qb, 512, 0, 512, qscale, nullptr);
    } else if (bid < 320) {
        // k = gstate @ Wk.T + bk -> bf16  [8192 x 512], grid 64x4
        int lb = bid - 64;
        gemm_body<0, 1, 0>(dsm, lb & 63, lb >> 6, 0,
            gstate, 512, 0, Wk, 512, 0, bk, kb, 512, 0, 512, 1.f, nullptr);
    } else if (bid < 576) {
        // v = gstate @ Wv.T + bv -> vT[b][d][t] bf16, grid 64x4
        int lb = bid - 320;
        gemm_body<0, 2, 0>(dsm, lb & 63, lb >> 6, 0,
            gstate, 512, 0, Wv, 512, 0, bv, vTb, 0, 0, 512, 1.f, nullptr);
    } else {
        // Wgen f32 -> bf16 (8 elems/thread), 8000 blocks; first 8 blocks zero gs
        int lb = bid - 576;
        if (lb < 8) gs[lb * 256 + threadIdx.x] = 0.f;
        long long i = (long long)lb * 256 + threadIdx.x;
        const float4* p = (const float4*)Wgen + i * 2;
        float4 a = p[0], b = p[1];
        union { unsigned short us[8]; int4 v; } pk;
        pk.us[0] = f2bf(a.x); pk.us[1] = f2bf(a.y); pk.us[2] = f2bf(a.z); pk.us[3] = f2bf(a.w);
        pk.us[4] = f2bf(b.x); pk.us[5] = f2bf(b.y); pk.us[6] = f2bf(b.z); pk.us[7] = f2bf(b.w);
        ((int4*)wgenb)[i] = pk.v;
    }
}

// ---------------- attention softmax over T, masked, in place; also emits bf16 copy
__global__ __launch_bounds__(256) void attn_softmax(
    float* __restrict__ scores, unsigned short* __restrict__ scores_bf,
    const unsigned char* __restrict__ mask)
{
    __shared__ float red[4];
    int row = blockIdx.x;
    int b = row & (BB - 1);
    float* p = scores + (long long)row * TT;
    unsigned short* pb = scores_bf + (long long)row * TT;
    const unsigned char* mr = mask + (long long)b * TT;
    float vals[TT / 256];
    float lmax = -3.0e38f;
#pragma unroll
    for (int i = 0; i < TT / 256; i++) {
        int t = threadIdx.x + i * 256;
        float s = p[t];
        if (mr[t]) s = -1.0e9f;
        vals[i] = s;
        lmax = fmaxf(lmax, s);
    }
    float gmax = block_red_max(lmax, red);
    float lsum = 0.f;
#pragma unroll
    for (int i = 0; i < TT / 256; i++) {
        vals[i] = __expf(vals[i] - gmax);
        lsum += vals[i];
    }
    float gsum = block_red_sum(lsum, red);
    float inv = 1.f / gsum;
#pragma unroll
    for (int i = 0; i < TT / 256; i++) {
        float v = vals[i] * inv;
        int t = threadIdx.x + i * 256;
        p[t] = v;
        pb[t] = f2bf(v);
    }
}

// ---------------- y = LayerNorm(outs + xo) * g + b
__global__ __launch_bounds__(256) void add_ln(
    const float* __restrict__ outs, const float* __restrict__ xo,
    const float* __restrict__ g, const float* __restrict__ bln,
    float* __restrict__ y)
{
    __shared__ float red[4];
    int row = blockIdx.x;
    const float* o = outs + (long long)row * DD;
    const float* xp = xo + (long long)row * DD;
    float x[DD / 256];
    float s = 0.f;
#pragma unroll
    for (int i = 0; i < DD / 256; i++) {
        int d = threadIdx.x + i * 256;
        x[i] = o[d] + xp[d];
        s += x[i];
    }
    float mu = block_red_sum(s, red) * (1.f / DD);
    float s2 = 0.f;
#pragma unroll
    for (int i = 0; i < DD / 256; i++) {
        float dv = x[i] - mu;
        s2 += dv * dv;
    }
    float var = block_red_sum(s2, red) * (1.f / DD);
    float rinv = rsqrtf(var + LN_EPS_F);
#pragma unroll
    for (int i = 0; i < DD / 256; i++) {
        int d = threadIdx.x + i * 256;
        y[(long long)row * DD + d] = (x[i] - mu) * rinv * g[d] + bln[d];
    }
}

// ---------------- fused gates + copy-scatter + normalize + log
// One block per (row, V-half). Gates recomputed per block from tokb row (cheap);
// LDS pc[] accumulates copy contributions; stream: ll = log(E*gen/gs + pc + 1e-12).
__global__ __launch_bounds__(512) void copy_log_final(
    const unsigned short* __restrict__ eb, const float* __restrict__ attn,
    const unsigned short* __restrict__ tok, const float* __restrict__ Wdiv,
    const float* __restrict__ bdiv, const float* __restrict__ gs,
    const int* __restrict__ seq, float* __restrict__ out)
{
    __shared__ __align__(16) float pc[VHALF];          // 64000 B
    __shared__ float red[8];
    const int tid = threadIdx.x;
    const int row = blockIdx.x;          // (s,b) row, b = row & 7
    const int half = blockIdx.y;
    const int base = half * VHALF;
    const int b = row & (BB - 1);

    for (int i = tid; i < VHALF; i += 512) pc[i] = 0.f;

    // gates: a = tok_row . Wdiv + bdiv ; softmax2  (512 threads = 1 elem each)
    float tv = bf2f(tok[(long long)row * TSD + tid]);
    float a0 = tv * Wdiv[tid];
    float a1 = tv * Wdiv[TSD + tid];
    a0 = block_red_sum(a0, red);
    a1 = block_red_sum(a1, red);
    a0 += bdiv[0];
    a1 += bdiv[1];
    float mx = fmaxf(a0, a1);
    float e0 = __expf(a0 - mx), e1 = __expf(a1 - mx);
    float inv2 = 1.f / (e0 + e1);
    const float cv = e1 * inv2;                 // copy gate
    const float ginv = (e0 * inv2) / gs[row];   // gen gate / rowsum
    __syncthreads();

    const float* arow = attn + (long long)row * TT;
#pragma unroll
    for (int it = 0; it < 2; it++) {
        int t = tid + it * 512;
        int idx = seq[t * BB + b];
        int loc = idx - base;
        if (loc >= 0 && loc < VHALF)
            atomicAdd(&pc[loc], cv * arow[t]);
    }
    __syncthreads();

    const unsigned short* erow = eb + (long long)row * VV + base;
    float* orow = out + (long long)row * VV + base;
    const float4* pc4 = (const float4*)pc;
    for (int c = tid; c < VHALF / 8; c += 512) {
        bf16x8 ev = *(const bf16x8*)(erow + c * 8);
        float4 p0 = pc4[c * 2], p1 = pc4[c * 2 + 1];
        float4 o0, o1;
        o0.x = __logf(fmaf(bf2f((unsigned short)ev[0]), ginv, p0.x) + 1e-12f);
        o0.y = __logf(fmaf(bf2f((unsigned short)ev[1]), ginv, p0.y) + 1e-12f);
        o0.z = __logf(fmaf(bf2f((unsigned short)ev[2]), ginv, p0.z) + 1e-12f);
        o0.w = __logf(fmaf(bf2f((unsigned short)ev[3]), ginv, p0.w) + 1e-12f);
        o1.x = __logf(fmaf(bf2f((unsigned short)ev[4]), ginv, p1.x) + 1e-12f);
        o1.y = __logf(fmaf(bf2f((unsigned short)ev[5]), ginv, p1.y) + 1e-12f);
        o1.z = __logf(fmaf(bf2f((unsigned short)ev[6]), ginv, p1.z) + 1e-12f);
        o1.w = __logf(fmaf(bf2f((unsigned short)ev[7]), ginv, p1.w) + 1e-12f);
        ((float4*)orow)[c * 2] = o0;
        ((float4*)orow)[c * 2 + 1] = o1;
    }
}

extern "C" void kernel_launch(void* const* d_in, const int* in_sizes, int n_in,
                              void* d_out, int out_size, void* d_ws, size_t ws_size,
                              hipStream_t stream)
{
    const float* outs = (const float*)d_in[0];
    const float* gstate = (const float*)d_in[1];
    const unsigned char* mask = (const unsigned char*)d_in[2];
    const int* seq = (const int*)d_in[3];
    const float* Wq = (const float*)d_in[4];  const float* bq = (const float*)d_in[5];
    const float* Wk = (const float*)d_in[6];  const float* bk = (const float*)d_in[7];
    const float* Wv = (const float*)d_in[8];  const float* bv = (const float*)d_in[9];
    const float* Wo = (const float*)d_in[10]; const float* bo = (const float*)d_in[11];
    const float* lng = (const float*)d_in[12]; const float* lnb = (const float*)d_in[13];
    const float* Wt = (const float*)d_in[14]; const float* bt = (const float*)d_in[15];
    const float* Wgen = (const float*)d_in[16]; const float* bgen = (const float*)d_in[17];
    const float* Wdiv = (const float*)d_in[18]; const float* bdiv = (const float*)d_in[19];
    float* out = (float*)d_out;

    char* w = (char*)d_ws;
    unsigned short* qb    = (unsigned short*)w; w += 2048LL * 512 * 2;   // q bf16
    unsigned short* kb    = (unsigned short*)w; w += 8192LL * 512 * 2;   // k bf16
    unsigned short* tokb  = (unsigned short*)w; w += 2048LL * 512 * 2;   // tok bf16
    unsigned short* wgenb = (unsigned short*)w; w += 32000LL * 512 * 2;  // Wgen bf16
    unsigned short* vTb   = (unsigned short*)w; w += 8LL * 512 * 1024 * 2; // v^T bf16 [b][d][t]
    unsigned short* attnb = (unsigned short*)w; w += 2048LL * 1024 * 2;  // attn bf16
    unsigned short* eb    = (unsigned short*)w; w += 2048LL * 32000 * 2; // E = exp(logits) bf16
    float* attn = (float*)w; w += 2048LL * 1024 * 4;
    float* ctx  = (float*)w; w += 2048LL * 512 * 4;
    float* xo   = (float*)w; w += 2048LL * 512 * 4;
    float* y    = (float*)w; w += 2048LL * 512 * 4;
    float* gs   = (float*)w; w += 2048 * 4;

    float qscale = 1.0f / sqrtf((float)DD);
    dim3 blk(256);

    // q | k | v->vT | Wgen cast + gs zero, one launch (64+256+256+8000 blocks)
    front_fused<<<8576, blk, 32768, stream>>>(outs, Wq, bq, gstate, Wk, bk, Wv, bv,
                                              qb, kb, vTb, Wgen, wgenb, gs, qscale);
    // scores[s,b,t] = q . k per batch        [256 x 1024, z=8]
    mfma_gemm<1, 0, 0, 0><<<dim3(2, 8, 8), blk, 0, stream>>>(qb, 4096, 512, kb, 4096, 512, nullptr, attn, 8192, 1024, 512, 1.f, nullptr);
    attn_softmax<<<2048, blk, 0, stream>>>(attn, attnb, mask);
    // ctx = attn @ v per batch via MFMA: C[s,d] = sum_t attnb[s,t] * vT[d,t]
    mfma_gemm<1, 0, 0, 0><<<dim3(2, 4, 8), blk, 0, stream>>>(attnb, 8192, 1024, vTb, 1024, 524288, nullptr, ctx, 4096, 512, 1024, 1.f, nullptr);
    // xo = ctx @ Wo.T + bo
    mfma_gemm<0, 0, 0, 0><<<dim3(16, 4, 1), blk, 0, stream>>>(ctx, 512, 0, Wo, 512, 0, bo, xo, 512, 0, 512, 1.f, nullptr);
    add_ln<<<2048, blk, 0, stream>>>(outs, xo, lng, lnb, y);
    // tok = tanh(y @ Wt.T + bt) -> bf16
    mfma_gemm<0, 1, 1, 0><<<dim3(16, 4, 1), blk, 0, stream>>>(y, 512, 0, Wt, 512, 0, bt, tokb, 512, 0, 512, 1.f, nullptr);
    // E = exp(tok @ Wgen.T + bgen) -> eb (bf16), row sums -> gs   [2048 x 32000]
    mfma_gemm<1, 1, 2, 1><<<dim3(16, 250, 1), blk, 0, stream>>>(tokb, 512, 0, wgenb, 512, 0, bgen, eb, 32000, 0, 512, 1.f, gs);
    // ll = log(E*gen/gs + copy + 1e-12); gates recomputed in-block; copy via LDS scatter
    copy_log_final<<<dim3(2048, 2), dim3(512), 0, stream>>>(eb, attn, tokb, Wdiv, bdiv, gs, seq, out);
}

// Round 8
// 684.063 us; speedup vs baseline: 1.1295x; 1.0267x over previous
//
#include <hip/hip_runtime.h>
#include <hip/hip_bf16.h>
#include <math.h>

#define SS 256
#define BB 8
#define TT 1024
#define DD 512
#define TSD 512
#define VV 32000
#define LN_EPS_F 1e-5f
#define VHALF 16000

typedef __attribute__((ext_vector_type(8))) short bf16x8;
typedef __attribute__((ext_vector_type(4))) float f32x4;

__device__ __forceinline__ unsigned short f2bf(float f) {
    union { float f; unsigned int u; } c; c.f = f;
    unsigned int u = c.u;
    return (unsigned short)((u + 0x7fffu + ((u >> 16) & 1u)) >> 16);
}
__device__ __forceinline__ float bf2f(unsigned short s) {
    union { unsigned int u; float f; } c; c.u = ((unsigned int)s) << 16;
    return c.f;
}

// async 16B global->LDS (wave-uniform LDS base + lane*16 by construction of callers)
__device__ __forceinline__ void glls16(const void* g, void* l) {
    __builtin_amdgcn_global_load_lds(
        (const __attribute__((address_space(1))) unsigned int*)g,
        (__attribute__((address_space(3))) unsigned int*)l,
        16, 0, 0);
}

// ---------------- reductions ----------------
__device__ __forceinline__ float warp_red_sum(float v) {
    for (int o = 32; o > 0; o >>= 1) v += __shfl_down(v, o, 64);
    return v;
}
__device__ __forceinline__ float warp_red_max(float v) {
    for (int o = 32; o > 0; o >>= 1) v = fmaxf(v, __shfl_down(v, o, 64));
    return v;
}
__device__ __forceinline__ float block_red_sum(float v, float* s) {
    int lane = threadIdx.x & 63, wid = threadIdx.x >> 6;
    v = warp_red_sum(v);
    __syncthreads();
    if (lane == 0) s[wid] = v;
    __syncthreads();
    float r = 0.f;
    int nw = blockDim.x >> 6;
    for (int i = 0; i < nw; i++) r += s[i];
    return r;
}
__device__ __forceinline__ float block_red_max(float v, float* s) {
    int lane = threadIdx.x & 63, wid = threadIdx.x >> 6;
    v = warp_red_max(v);
    __syncthreads();
    if (lane == 0) s[wid] = v;
    __syncthreads();
    float r = s[0];
    int nw = blockDim.x >> 6;
    for (int i = 1; i < nw; i++) r = fmaxf(r, s[i]);
    return r;
}

// ---------------- MFMA GEMM body (NT): C[m,n] = act((sum_k A[m,k]*B[n,k] + bias[n]) * scale)
// 128x128 tile, BK=64, 256 threads = 4 waves (2x2), each wave 4x4 tiles of 16x16x32.
// LDS chunk layout: chunk c (16B = 8 bf16) holds (row = c>>3, kc_logical = (c&7) ^ (row&7)).
// ACT: 0 none | 1 tanh | 2 exp + rowsum->rsum | 3 residual: v+=outs[idx], write f32,
//      accumulate rowsum->rsum & rowsumsq->rsum2 (for downstream inline LayerNorm)
// LN_A: A-staging applies (a-mu)*rinv*g+b with mu/rinv from lnrs/lnrss row moments
// DUALA: A := Ap + Ap2 elementwise (split-K partial merge)
// OUT_MODE: 0 f32 scattered | 1 bf16 LDS-staged coalesced | 2 bf16 direct into vT[b][d][t]
template<int IN_BF16, int OUT_MODE, int ACT, int LN_A, int DUALA>
__device__ __forceinline__ void gemm_body(
    unsigned short* smem, int bx, int by, int z,
    const void* __restrict__ Ap, const void* __restrict__ Ap2,
    long long lda, long long aoff,
    const void* __restrict__ Bp, long long ldb, long long boff,
    const float* __restrict__ bias,
    void* __restrict__ Cp, long long ldc, long long coff,
    int K, float scale, float* __restrict__ rsum, float* __restrict__ rsum2,
    const float* __restrict__ outsP,
    const float* __restrict__ lnrs, const float* __restrict__ lnrss,
    const float* __restrict__ lng, const float* __restrict__ lnbp)
{
    unsigned short* As = smem;
    unsigned short* Bs = smem + 128 * 64;
    const int tid = threadIdx.x;
    const int lane = tid & 63;
    const int wave = tid >> 6;
    const int wm = (wave >> 1) << 6;
    const int wn = (wave & 1) << 6;
    const int lane15 = lane & 15;
    const int quad = lane >> 4;
    const long long m0 = (long long)bx * 128;
    const long long n0 = (long long)by * 128;

    f32x4 acc[4][4];
#pragma unroll
    for (int i = 0; i < 4; i++)
#pragma unroll
        for (int j = 0; j < 4; j++) acc[i][j] = (f32x4){0.f, 0.f, 0.f, 0.f};

    for (int k0 = 0; k0 < K; k0 += 64) {
        if (IN_BF16) {
            const unsigned short* A = (const unsigned short*)Ap + z * aoff;
            const unsigned short* B = (const unsigned short*)Bp + z * boff;
#pragma unroll
            for (int r = 0; r < 4; r++) {
                int c = r * 256 + tid;
                int row = c >> 3;
                int kc = (c & 7) ^ (row & 7);
                glls16(A + (m0 + row) * lda + k0 + kc * 8, &As[c * 8]);
                glls16(B + (n0 + row) * ldb + k0 + kc * 8, &Bs[c * 8]);
            }
        } else {
            const float* A = (const float*)Ap + z * aoff;
            const float* B = (const float*)Bp + z * boff;
#pragma unroll
            for (int r = 0; r < 4; r++) {
                int c = r * 256 + tid;
                int row = c >> 3;
                int kc = (c & 7) ^ (row & 7);
                const float* ga = A + (m0 + row) * lda + k0 + kc * 8;
                const float* gb = B + (n0 + row) * ldb + k0 + kc * 8;
                float4 a0 = *(const float4*)ga, a1 = *(const float4*)(ga + 4);
                float4 b0 = *(const float4*)gb, b1 = *(const float4*)(gb + 4);
                if (DUALA) {
                    const float* ga2 = (const float*)Ap2 + z * aoff + (m0 + row) * lda + k0 + kc * 8;
                    float4 c0 = *(const float4*)ga2, c1 = *(const float4*)(ga2 + 4);
                    a0.x += c0.x; a0.y += c0.y; a0.z += c0.z; a0.w += c0.w;
                    a1.x += c1.x; a1.y += c1.y; a1.z += c1.z; a1.w += c1.w;
                }
                if (LN_A) {
                    long long grow = m0 + row;
                    float mu = lnrs[grow] * (1.f / DD);
                    float var = lnrss[grow] * (1.f / DD) - mu * mu;
                    float rinv = rsqrtf(var + LN_EPS_F);
                    const float* gp = lng + k0 + kc * 8;
                    const float* bp = lnbp + k0 + kc * 8;
                    float4 g0 = *(const float4*)gp, g1 = *(const float4*)(gp + 4);
                    float4 e0 = *(const float4*)bp, e1 = *(const float4*)(bp + 4);
                    a0.x = (a0.x - mu) * rinv * g0.x + e0.x;
                    a0.y = (a0.y - mu) * rinv * g0.y + e0.y;
                    a0.z = (a0.z - mu) * rinv * g0.z + e0.z;
                    a0.w = (a0.w - mu) * rinv * g0.w + e0.w;
                    a1.x = (a1.x - mu) * rinv * g1.x + e1.x;
                    a1.y = (a1.y - mu) * rinv * g1.y + e1.y;
                    a1.z = (a1.z - mu) * rinv * g1.z + e1.z;
                    a1.w = (a1.w - mu) * rinv * g1.w + e1.w;
                }
                union { unsigned short us[8]; int4 v; } pa, pb;
                pa.us[0] = f2bf(a0.x); pa.us[1] = f2bf(a0.y); pa.us[2] = f2bf(a0.z); pa.us[3] = f2bf(a0.w);
                pa.us[4] = f2bf(a1.x); pa.us[5] = f2bf(a1.y); pa.us[6] = f2bf(a1.z); pa.us[7] = f2bf(a1.w);
                pb.us[0] = f2bf(b0.x); pb.us[1] = f2bf(b0.y); pb.us[2] = f2bf(b0.z); pb.us[3] = f2bf(b0.w);
                pb.us[4] = f2bf(b1.x); pb.us[5] = f2bf(b1.y); pb.us[6] = f2bf(b1.z); pb.us[7] = f2bf(b1.w);
                *(int4*)&As[c * 8] = pa.v;
                *(int4*)&Bs[c * 8] = pb.v;
            }
        }
        __syncthreads();
#pragma unroll
        for (int s = 0; s < 2; s++) {
            bf16x8 af[4], bfr[4];
#pragma unroll
            for (int i = 0; i < 4; i++) {
                int arow = wm + i * 16 + lane15;
                int kc = (s * 4 + quad) ^ (lane15 & 7);
                af[i] = *(const bf16x8*)&As[(arow * 8 + kc) * 8];
                int brow = wn + i * 16 + lane15;
                bfr[i] = *(const bf16x8*)&Bs[(brow * 8 + kc) * 8];
            }
#pragma unroll
            for (int i = 0; i < 4; i++)
#pragma unroll
                for (int j = 0; j < 4; j++)
                    acc[i][j] = __builtin_amdgcn_mfma_f32_16x16x32_bf16(af[i], bfr[j], acc[i][j], 0, 0, 0);
        }
        __syncthreads();
    }
    // ---- epilogue: C/D layout col=lane&15, row=quad*4+reg [m89/m91 verified] ----
    const long long zc = z * coff;
    float* sRowF = (float*)&smem[0];
    if (ACT == 2) {
        if (tid < 128) sRowF[tid] = 0.f;
        __syncthreads();
    }
    if (ACT == 3) {
        if (tid < 256) sRowF[tid] = 0.f;     // [0:128) sum, [128:256) sumsq
        __syncthreads();
    }
#pragma unroll
    for (int i = 0; i < 4; i++) {
        const long long rbase = m0 + wm + i * 16 + quad * 4;
        float rs_[4] = {0.f, 0.f, 0.f, 0.f};
        float rq_[4] = {0.f, 0.f, 0.f, 0.f};
#pragma unroll
        for (int j = 0; j < 4; j++) {
            long long col = n0 + wn + j * 16 + lane15;
            float bv = bias ? bias[col] : 0.f;
#pragma unroll
            for (int r2 = 0; r2 < 4; r2++) {
                float v = (acc[i][j][r2] + bv) * scale;
                if (ACT == 1) v = tanhf(v);
                if (ACT == 2) { v = __expf(v); rs_[r2] += v; }
                if (ACT == 3) {
                    long long idx = zc + (rbase + r2) * ldc + col;
                    v += outsP[idx];
                    ((float*)Cp)[idx] = v;
                    rs_[r2] += v;
                    rq_[r2] += v * v;
                }
                acc[i][j][r2] = v;
            }
        }
        if (ACT == 2 || ACT == 3) {
#pragma unroll
            for (int r2 = 0; r2 < 4; r2++) {
                float s = rs_[r2];
                s += __shfl_xor(s, 1, 64);
                s += __shfl_xor(s, 2, 64);
                s += __shfl_xor(s, 4, 64);
                s += __shfl_xor(s, 8, 64);
                if (lane15 == 0) atomicAdd(&sRowF[wm + i * 16 + quad * 4 + r2], s);
                if (ACT == 3) {
                    float q = rq_[r2];
                    q += __shfl_xor(q, 1, 64);
                    q += __shfl_xor(q, 2, 64);
                    q += __shfl_xor(q, 4, 64);
                    q += __shfl_xor(q, 8, 64);
                    if (lane15 == 0) atomicAdd(&sRowF[128 + wm + i * 16 + quad * 4 + r2], q);
                }
            }
        }
    }
    if (ACT == 2) {
        __syncthreads();
        if (tid < 128) atomicAdd(rsum + m0 + tid, sRowF[tid]);
        __syncthreads();
    }
    if (ACT == 3) {
        __syncthreads();
        if (tid < 128) {
            atomicAdd(rsum + m0 + tid, sRowF[tid]);
            atomicAdd(rsum2 + m0 + tid, sRowF[128 + tid]);
        }
        return;   // C already written
    }
    if (OUT_MODE >= 1) {
        // stage the 128x128 bf16 tile in smem (32 KB), row-XOR swizzle to spread banks
#pragma unroll
        for (int i = 0; i < 4; i++) {
#pragma unroll
            for (int r2 = 0; r2 < 4; r2++) {
                int lr = wm + i * 16 + quad * 4 + r2;
                int sw = (lr & 7) << 4;
#pragma unroll
                for (int j = 0; j < 4; j++) {
                    int lc = wn + j * 16 + lane15;
                    smem[lr * 128 + (lc ^ sw)] = f2bf(acc[i][j][r2]);
                }
            }
        }
        __syncthreads();
        if (OUT_MODE == 1) {
            unsigned short* Co = (unsigned short*)Cp + zc;
#pragma unroll
            for (int u = 0; u < 8; u++) {
                int e = tid + u * 256;
                int lr = e >> 4, lc8 = e & 15;
                int lcs = (lc8 * 8) ^ ((lr & 7) << 4);
                int4 vv4 = *(const int4*)&smem[lr * 128 + lcs];
                *(int4*)(Co + (m0 + lr) * ldc + n0 + lc8 * 8) = vv4;
            }
        } else {
            // OUT_MODE 2: tile rows m = t*8+b; write vT[b][d][t] (32B per (b,d) pair)
            unsigned short* vT = (unsigned short*)Cp;
            const int t0g = (int)(m0 >> 3);
#pragma unroll
            for (int u = 0; u < 4; u++) {
                int e = tid + u * 256;
                int b = e >> 7, dl = e & 127;
                int sw = (b & 7) << 4;
                union { unsigned short us[16]; int4 v[2]; } pk;
#pragma unroll
                for (int tl = 0; tl < 16; tl++)
                    pk.us[tl] = smem[(tl * 8 + b) * 128 + (dl ^ sw)];
                unsigned short* dst = vT + (long long)b * (DD * TT) + (long long)(n0 + dl) * TT + t0g;
                *(int4*)dst = pk.v[0];
                *(int4*)(dst + 8) = pk.v[1];
            }
        }
        __syncthreads();
    } else {
#pragma unroll
        for (int i = 0; i < 4; i++) {
            long long rbase = m0 + wm + i * 16 + quad * 4;
#pragma unroll
            for (int j = 0; j < 4; j++) {
                long long col = n0 + wn + j * 16 + lane15;
#pragma unroll
                for (int r2 = 0; r2 < 4; r2++)
                    ((float*)Cp)[zc + (rbase + r2) * ldc + col] = acc[i][j][r2];
            }
        }
    }
}

// ---------------- standalone GEMM kernel wrapper
template<int IN_BF16, int OUT_MODE, int ACT, int LN_A, int DUALA, int SWZ>
__global__ __launch_bounds__(256) void mfma_gemm(
    const void* __restrict__ Ap, const void* __restrict__ Ap2,
    long long lda, long long aoff,
    const void* __restrict__ Bp, long long ldb, long long boff,
    const float* __restrict__ bias,
    void* __restrict__ Cp, long long ldc, long long coff,
    int K, float scale, float* __restrict__ rsum, float* __restrict__ rsum2,
    const float* __restrict__ outsP,
    const float* __restrict__ lnrs, const float* __restrict__ lnrss,
    const float* __restrict__ lng, const float* __restrict__ lnbp)
{
    __shared__ __align__(16) unsigned short smem[2 * 128 * 64];
    int bx = blockIdx.x, by = blockIdx.y;
    if (SWZ) {
        unsigned int nx = gridDim.x;
        unsigned int nwg = nx * gridDim.y;
        unsigned int lin = blockIdx.y * nx + blockIdx.x;
        unsigned int q = nwg >> 3, r = nwg & 7u;
        unsigned int xcd = lin & 7u, loc = lin >> 3;
        unsigned int wg = (xcd < r ? xcd * (q + 1u) : r * (q + 1u) + (xcd - r) * q) + loc;
        bx = (int)(wg % nx);
        by = (int)(wg / nx);
    }
    gemm_body<IN_BF16, OUT_MODE, ACT, LN_A, DUALA>(smem, bx, by, blockIdx.z,
        Ap, Ap2, lda, aoff, Bp, ldb, boff, bias, Cp, ldc, coff, K, scale,
        rsum, rsum2, outsP, lnrs, lnrss, lng, lnbp);
}

// ---------------- split-K (x2) bf16 GEMM: z = (kz<<3)|b; writes partials C0/C1
__global__ __launch_bounds__(256) void mfma_gemm_splitk(
    const unsigned short* __restrict__ Ap, long long lda, long long aoff,
    const unsigned short* __restrict__ Bp, long long ldb, long long boff,
    float* __restrict__ C0, float* __restrict__ C1,
    long long ldc, long long coff, int Khalf)
{
    __shared__ __align__(16) unsigned short smem[2 * 128 * 64];
    int b = blockIdx.z & 7, kz = blockIdx.z >> 3;
    const unsigned short* A = Ap + (long long)kz * Khalf;
    const unsigned short* B = Bp + (long long)kz * Khalf;
    float* C = kz ? C1 : C0;
    gemm_body<1, 0, 0, 0, 0>(smem, blockIdx.x, blockIdx.y, b,
        A, nullptr, lda, aoff, B, ldb, boff, nullptr, C, ldc, coff, Khalf, 1.f,
        nullptr, nullptr, nullptr, nullptr, nullptr, nullptr, nullptr);
}

// ---------------- fused front: q-GEMM | k-GEMM | v-GEMM(->vT) | Wgen cast + accum zero
__global__ __launch_bounds__(256) void front_fused(
    const float* __restrict__ outs, const float* __restrict__ Wq, const float* __restrict__ bq,
    const float* __restrict__ gstate, const float* __restrict__ Wk, const float* __restrict__ bk,
    const float* __restrict__ Wv, const float* __restrict__ bv,
    unsigned short* __restrict__ qb, unsigned short* __restrict__ kb,
    unsigned short* __restrict__ vTb,
    const float* __restrict__ Wgen, unsigned short* __restrict__ wgenb,
    float* __restrict__ gs, float* __restrict__ rs, float* __restrict__ rss,
    float qscale)
{
    extern __shared__ __align__(16) unsigned short dsm[];
    const int bid = blockIdx.x;
    if (bid < 64) {
        gemm_body<0, 1, 0, 0, 0>(dsm, bid & 15, bid >> 4, 0,
            outs, nullptr, 512, 0, Wq, 512, 0, bq, qb, 512, 0, 512, qscale,
            nullptr, nullptr, nullptr, nullptr, nullptr, nullptr, nullptr);
    } else if (bid < 320) {
        int lb = bid - 64;
        gemm_body<0, 1, 0, 0, 0>(dsm, lb & 63, lb >> 6, 0,
            gstate, nullptr, 512, 0, Wk, 512, 0, bk, kb, 512, 0, 512, 1.f,
            nullptr, nullptr, nullptr, nullptr, nullptr, nullptr, nullptr);
    } else if (bid < 576) {
        int lb = bid - 320;
        gemm_body<0, 2, 0, 0, 0>(dsm, lb & 63, lb >> 6, 0,
            gstate, nullptr, 512, 0, Wv, 512, 0, bv, vTb, 0, 0, 512, 1.f,
            nullptr, nullptr, nullptr, nullptr, nullptr, nullptr, nullptr);
    } else {
        int lb = bid - 576;
        if (lb < 8) {
            int i = lb * 256 + threadIdx.x;
            gs[i] = 0.f; rs[i] = 0.f; rss[i] = 0.f;
        }
        long long i = (long long)lb * 256 + threadIdx.x;
        const float4* p = (const float4*)Wgen + i * 2;
        float4 a = p[0], b = p[1];
        union { unsigned short us[8]; int4 v; } pk;
        pk.us[0] = f2bf(a.x); pk.us[1] = f2bf(a.y); pk.us[2] = f2bf(a.z); pk.us[3] = f2bf(a.w);
        pk.us[4] = f2bf(b.x); pk.us[5] = f2bf(b.y); pk.us[6] = f2bf(b.z); pk.us[7] = f2bf(b.w);
        ((int4*)wgenb)[i] = pk.v;
    }
}

// ---------------- attention softmax: sums split-K partials, masked, emits bf16 only
__global__ __launch_bounds__(256) void attn_softmax(
    const float* __restrict__ s0, const float* __restrict__ s1,
    unsigned short* __restrict__ scores_bf, const unsigned char* __restrict__ mask)
{
    __shared__ float red[4];
    int row = blockIdx.x;
    int b = row & (BB - 1);
    const float* p0 = s0 + (long long)row * TT;
    const float* p1 = s1 + (long long)row * TT;
    unsigned short* pb = scores_bf + (long long)row * TT;
    const unsigned char* mr = mask + (long long)b * TT;
    float vals[TT / 256];
    float lmax = -3.0e38f;
#pragma unroll
    for (int i = 0; i < TT / 256; i++) {
        int t = threadIdx.x + i * 256;
        float s = p0[t] + p1[t];
        if (mr[t]) s = -1.0e9f;
        vals[i] = s;
        lmax = fmaxf(lmax, s);
    }
    float gmax = block_red_max(lmax, red);
    float lsum = 0.f;
#pragma unroll
    for (int i = 0; i < TT / 256; i++) {
        vals[i] = __expf(vals[i] - gmax);
        lsum += vals[i];
    }
    float gsum = block_red_sum(lsum, red);
    float inv = 1.f / gsum;
#pragma unroll
    for (int i = 0; i < TT / 256; i++)
        pb[threadIdx.x + i * 256] = f2bf(vals[i] * inv);
}

// ---------------- fused gates + copy-scatter + normalize + log
__global__ __launch_bounds__(512) void copy_log_final(
    const unsigned short* __restrict__ eb, const unsigned short* __restrict__ attnb,
    const unsigned short* __restrict__ tok, const float* __restrict__ Wdiv,
    const float* __restrict__ bdiv, const float* __restrict__ gs,
    const int* __restrict__ seq, float* __restrict__ out)
{
    __shared__ __align__(16) float pc[VHALF];          // 64000 B
    __shared__ float red[8];
    const int tid = threadIdx.x;
    const int row = blockIdx.x;          // (s,b) row, b = row & 7
    const int half = blockIdx.y;
    const int base = half * VHALF;
    const int b = row & (BB - 1);

    for (int i = tid; i < VHALF; i += 512) pc[i] = 0.f;

    // gates: a = tok_row . Wdiv + bdiv ; softmax2  (512 threads = 1 elem each)
    float tv = bf2f(tok[(long long)row * TSD + tid]);
    float a0 = tv * Wdiv[tid];
    float a1 = tv * Wdiv[TSD + tid];
    a0 = block_red_sum(a0, red);
    a1 = block_red_sum(a1, red);
    a0 += bdiv[0];
    a1 += bdiv[1];
    float mx = fmaxf(a0, a1);
    float e0 = __expf(a0 - mx), e1 = __expf(a1 - mx);
    float inv2 = 1.f / (e0 + e1);
    const float cv = e1 * inv2;                 // copy gate
    const float ginv = (e0 * inv2) / gs[row];   // gen gate / rowsum
    __syncthreads();

    const unsigned short* arow = attnb + (long long)row * TT;
#pragma unroll
    for (int it = 0; it < 2; it++) {
        int t = tid + it * 512;
        int idx = seq[t * BB + b];
        int loc = idx - base;
        if (loc >= 0 && loc < VHALF)
            atomicAdd(&pc[loc], cv * bf2f(arow[t]));
    }
    __syncthreads();

    const unsigned short* erow = eb + (long long)row * VV + base;
    float* orow = out + (long long)row * VV + base;
    const float4* pc4 = (const float4*)pc;
    for (int c = tid; c < VHALF / 8; c += 512) {
        bf16x8 ev = *(const bf16x8*)(erow + c * 8);
        float4 p0 = pc4[c * 2], p1 = pc4[c * 2 + 1];
        float4 o0, o1;
        o0.x = __logf(fmaf(bf2f((unsigned short)ev[0]), ginv, p0.x) + 1e-12f);
        o0.y = __logf(fmaf(bf2f((unsigned short)ev[1]), ginv, p0.y) + 1e-12f);
        o0.z = __logf(fmaf(bf2f((unsigned short)ev[2]), ginv, p0.z) + 1e-12f);
        o0.w = __logf(fmaf(bf2f((unsigned short)ev[3]), ginv, p0.w) + 1e-12f);
        o1.x = __logf(fmaf(bf2f((unsigned short)ev[4]), ginv, p1.x) + 1e-12f);
        o1.y = __logf(fmaf(bf2f((unsigned short)ev[5]), ginv, p1.y) + 1e-12f);
        o1.z = __logf(fmaf(bf2f((unsigned short)ev[6]), ginv, p1.z) + 1e-12f);
        o1.w = __logf(fmaf(bf2f((unsigned short)ev[7]), ginv, p1.w) + 1e-12f);
        ((float4*)orow)[c * 2] = o0;
        ((float4*)orow)[c * 2 + 1] = o1;
    }
}

extern "C" void kernel_launch(void* const* d_in, const int* in_sizes, int n_in,
                              void* d_out, int out_size, void* d_ws, size_t ws_size,
                              hipStream_t stream)
{
    const float* outs = (const float*)d_in[0];
    const float* gstate = (const float*)d_in[1];
    const unsigned char* mask = (const unsigned char*)d_in[2];
    const int* seq = (const int*)d_in[3];
    const float* Wq = (const float*)d_in[4];  const float* bq = (const float*)d_in[5];
    const float* Wk = (const float*)d_in[6];  const float* bk = (const float*)d_in[7];
    const float* Wv = (const float*)d_in[8];  const float* bv = (const float*)d_in[9];
    const float* Wo = (const float*)d_in[10]; const float* bo = (const float*)d_in[11];
    const float* lng = (const float*)d_in[12]; const float* lnb = (const float*)d_in[13];
    const float* Wt = (const float*)d_in[14]; const float* bt = (const float*)d_in[15];
    const float* Wgen = (const float*)d_in[16]; const float* bgen = (const float*)d_in[17];
    const float* Wdiv = (const float*)d_in[18]; const float* bdiv = (const float*)d_in[19];
    float* out = (float*)d_out;

    char* w = (char*)d_ws;
    unsigned short* qb    = (unsigned short*)w; w += 2048LL * 512 * 2;   // q bf16
    unsigned short* kb    = (unsigned short*)w; w += 8192LL * 512 * 2;   // k bf16
    unsigned short* tokb  = (unsigned short*)w; w += 2048LL * 512 * 2;   // tok bf16
    unsigned short* wgenb = (unsigned short*)w; w += 32000LL * 512 * 2;  // Wgen bf16
    unsigned short* vTb   = (unsigned short*)w; w += 8LL * 512 * 1024 * 2; // v^T bf16 [b][d][t]
    unsigned short* attnb = (unsigned short*)w; w += 2048LL * 1024 * 2;  // attn bf16
    unsigned short* eb    = (unsigned short*)w; w += 2048LL * 32000 * 2; // E = exp(logits) bf16
    float* attn0 = (float*)w; w += 2048LL * 1024 * 4;  // qk split-K partials
    float* attn1 = (float*)w; w += 2048LL * 1024 * 4;
    float* ctx0  = (float*)w; w += 2048LL * 512 * 4;   // ctx split-K partials
    float* ctx1  = (float*)w; w += 2048LL * 512 * 4;
    float* sres  = (float*)w; w += 2048LL * 512 * 4;   // s = outs + xo
    float* gs    = (float*)w; w += 2048 * 4;           // exp rowsum
    float* rs    = (float*)w; w += 2048 * 4;           // s rowsum
    float* rss   = (float*)w; w += 2048 * 4;           // s rowsumsq

    float qscale = 1.0f / sqrtf((float)DD);
    dim3 blk(256);

    // q | k | v->vT | Wgen cast + zero accumulators, one launch
    front_fused<<<8576, blk, 32768, stream>>>(outs, Wq, bq, gstate, Wk, bk, Wv, bv,
                                              qb, kb, vTb, Wgen, wgenb, gs, rs, rss, qscale);
    // scores partials: split-K over D=512 (2x256), grid 256 blocks
    mfma_gemm_splitk<<<dim3(2, 8, 16), blk, 0, stream>>>(qb, 4096, 512, kb, 4096, 512,
                                                         attn0, attn1, 8192, 1024, 256);
    attn_softmax<<<2048, blk, 0, stream>>>(attn0, attn1, attnb, mask);
    // ctx partials: split-K over T=1024 (2x512), grid 128 blocks
    mfma_gemm_splitk<<<dim3(2, 4, 16), blk, 0, stream>>>(attnb, 8192, 1024, vTb, 1024, 524288,
                                                         ctx0, ctx1, 4096, 512, 512);
    // s = outs + (ctx0+ctx1) @ Wo.T + bo; row moments -> rs, rss
    mfma_gemm<0, 0, 3, 0, 1, 0><<<dim3(16, 4, 1), blk, 0, stream>>>(
        ctx0, ctx1, 512, 0, Wo, 512, 0, bo, sres, 512, 0, 512, 1.f,
        rs, rss, outs, nullptr, nullptr, nullptr, nullptr);
    // tok = tanh(LN(s)*g+b @ Wt.T + bt) -> bf16; LN applied inline in A-staging
    mfma_gemm<0, 1, 1, 1, 0, 0><<<dim3(16, 4, 1), blk, 0, stream>>>(
        sres, nullptr, 512, 0, Wt, 512, 0, bt, tokb, 512, 0, 512, 1.f,
        nullptr, nullptr, nullptr, rs, rss, lng, lnb);
    // E = exp(tok @ Wgen.T + bgen) -> eb (bf16), row sums -> gs
    mfma_gemm<1, 1, 2, 0, 0, 1><<<dim3(16, 250, 1), blk, 0, stream>>>(
        tokb, nullptr, 512, 0, wgenb, 512, 0, bgen, eb, 32000, 0, 512, 1.f,
        gs, nullptr, nullptr, nullptr, nullptr, nullptr, nullptr);
    // ll = log(E*gen/gs + copy + 1e-12); gates in-block; copy via LDS scatter
    copy_log_final<<<dim3(2048, 2), dim3(512), 0, stream>>>(eb, attnb, tokb, Wdiv, bdiv, gs, seq, out);
}